// Round 15
// baseline (123.382 us; speedup 1.0000x reference)
//
#include <hip/hip_runtime.h>
#include <cmath>

#define BB   8
#define NPIX 256
#define MM   8192
#define NCP  24576
#define NCA  24576
#define EPSF 1e-16f

#define KC   32    // K-chunk (y's per chunk) = one MFMA K-step
#define TMB  64    // m's per block

// ---- d_out layout (floats)
#define VIS_OFF    0
#define VISAMP_OFF (BB * 2 * MM)            // 131072
#define CPH_OFF    (VISAMP_OFF + BB * MM)   // 196608
#define LCA_OFF    (CPH_OFF + BB * NCP)     // 393216

typedef __bf16 bf16x8 __attribute__((ext_vector_type(8)));
typedef unsigned short u16x8 __attribute__((ext_vector_type(8)));
typedef float  f32x4  __attribute__((ext_vector_type(4)));

// Window layout: a tile of R rows x 32 k is stored as windows of 512 elements
// (16 rows each); element (row, k) lives at
//   (row>>4)*512 + (k>>3)*128 + (row&15)*8 + (k&7)
// All staging writes and fragment reads have 16 B lane stride within each
// 16-lane phase -> 2-way bank aliasing only (free, m136). 16B-aligned b128s.
// SESSION RULES (hard-won):
//  - do NOT pipeline data between kernels through d_ws (R5/R6 sporadic
//    corruption); d_out dataflow is proven.
//  - acc = 128 AGPR + ~100 VGPR: ONLY 2 waves/SIMD fits (reg steps 64/128/256).
//    >=4 waves/SIMD spills catastrophically (R8/R10). Keep launch_bounds(256,2).
//  - NUMERICS: keep the full 3-term split (R12: 2-term -> cphase 361 deg).
//    Angle outputs forbid kdata shortcuts. Rotor drift ~2e-6 is OK.
//  - gather: ~58 us residual is INVARIANT across libm/poly/LDS-staged gather
//    implementations (R9/R11/R13) -> suspected fixed harness cost; only the
//    vis kernel is a controllable lever now.
#define WIDX(row, k8) (((row) >> 4) * 512 + (k8) * 128 + ((row) & 15) * 8)

// truncation split: hi = top 16 bits of v (a valid bf16; v - hi is EXACT in
// fp32), lo = RNE bf16 of the exact residual. Total rep error ~2^-17 * |v|.
// Returned packed: low 16 = hi, high 16 = lo.
__device__ __forceinline__ unsigned tsplit(float v)
{
    const unsigned u = __float_as_uint(v);
    const float l = v - __uint_as_float(u & 0xFFFF0000u);
    const __bf16 lb = (__bf16)l;
    return (u >> 16) | ((unsigned)*(const unsigned short*)&lb << 16);
}

// Block: 64 m's x 256 x's x 1 batch. Ev via 3 sincos + rotor recurrences
// (anchor advanced by rot32 across chunks). 3-term split MFMA per plane.
__global__ __launch_bounds__(256, 2)
void nufft_vis_mfma(const float* __restrict__ images,
                    const float* __restrict__ ktraj,
                    const float* __restrict__ pulsefac,
                    float* __restrict__ out)
{
    __shared__ __align__(16) __bf16 sArh[TMB * KC];   // 4 KB  Evr hi
    __shared__ __align__(16) __bf16 sArl[TMB * KC];   // 4 KB  Evr lo
    __shared__ __align__(16) __bf16 sAih[TMB * KC];   // 4 KB  Evi hi
    __shared__ __align__(16) __bf16 sAil[TMB * KC];   // 4 KB  Evi lo
    __shared__ __align__(16) __bf16 sBh[NPIX * KC];   // 16 KB img hi
    __shared__ __align__(16) __bf16 sBl[NPIX * KC];   // 16 KB img lo

    const int tid  = threadIdx.x;
    const int m0   = blockIdx.x * TMB;
    const int b    = blockIdx.y;
    const int lane = tid & 63;
    const int w    = tid >> 6;        // wave 0..3
    const int ln15 = lane & 15;
    const int q    = lane >> 4;       // k-octet 0..3

    // A staging roles: thread (w, lane) computes Ev row=lane, k-octet=w.
    // 16B lane stride within each 16-lane phase -> 2-way (free).
    const float kvm = ktraj[m0 + lane];
    float r1s, r1c, r32s, r32c, as_, ac_;
    sincosf(kvm, &r1s, &r1c);                         // rot1  = e^{-i*kvm} (via -s)
    sincosf(kvm * 32.0f, &r32s, &r32c);               // rot32 = e^{-i*kvm*32}
    sincosf(kvm * (float)(w * 8 - 128), &as_, &ac_);  // anchor at y0=0
    float anr = ac_, ani = -as_;
    const float* imgb = images + b * NPIX * NPIX + tid;  // B staging: x = tid
    const int ao = WIDX(lane, w);

    f32x4 acc[2][16];                 // [0]=real plane, [1]=imag plane
    #pragma unroll
    for (int rt = 0; rt < 2; ++rt)
        #pragma unroll
        for (int ct = 0; ct < 16; ++ct)
            acc[rt][ct] = (f32x4){0.f, 0.f, 0.f, 0.f};

    for (int y0 = 0; y0 < NPIX; y0 += KC) {
        // ---- stage A: Ev[m0+lane, y0+8*w .. +8) via anchor + rot1 recurrence
        {
            float er = anr, ei = ani;   // Ev = exp(-i*kv*(y-128))
            u16x8 vrh, vrl, vih, vil;
            #pragma unroll
            for (int j = 0; j < 8; ++j) {
                const unsigned pr_ = tsplit(er);
                vrh[j] = (unsigned short)(pr_ & 0xFFFFu);
                vrl[j] = (unsigned short)(pr_ >> 16);
                const unsigned pi_ = tsplit(ei);
                vih[j] = (unsigned short)(pi_ & 0xFFFFu);
                vil[j] = (unsigned short)(pi_ >> 16);
                const float nr = er * r1c + ei * r1s;   // *= e^{-i*kvm}
                const float ni = ei * r1c - er * r1s;
                er = nr; ei = ni;
            }
            *(u16x8*)&sArh[ao] = vrh;
            *(u16x8*)&sArl[ao] = vrl;
            *(u16x8*)&sAih[ao] = vih;
            *(u16x8*)&sAil[ao] = vil;
            // advance anchor to next chunk: *= e^{-i*kvm*32}
            const float nr = anr * r32c + ani * r32s;
            const float ni = ani * r32c - anr * r32s;
            anr = nr; ani = ni;
        }
        // ---- stage B: img[b, y0..y0+31, x=tid] -> hi/lo, window layout
        #pragma unroll
        for (int gg = 0; gg < 4; ++gg) {
            u16x8 bh, bl;
            #pragma unroll
            for (int j = 0; j < 8; ++j) {
                const unsigned p = tsplit(imgb[(y0 + gg * 8 + j) * NPIX]);
                bh[j] = (unsigned short)(p & 0xFFFFu);
                bl[j] = (unsigned short)(p >> 16);
            }
            const int bo = WIDX(tid, gg);
            *(u16x8*)&sBh[bo] = bh;
            *(u16x8*)&sBl[bo] = bl;
        }
        __syncthreads();

        // ---- MFMA: wave w owns A-rows [16w, 16w+16)
        const int aro = WIDX(w * 16 + ln15, q);
        const bf16x8 ah0 = *(const bf16x8*)&sArh[aro];
        const bf16x8 al0 = *(const bf16x8*)&sArl[aro];
        const bf16x8 ah1 = *(const bf16x8*)&sAih[aro];
        const bf16x8 al1 = *(const bf16x8*)&sAil[aro];

        #pragma unroll
        for (int ct = 0; ct < 16; ++ct) {
            const int bro = WIDX(ct * 16 + ln15, q);
            const bf16x8 bh = *(const bf16x8*)&sBh[bro];
            const bf16x8 bl = *(const bf16x8*)&sBl[bro];
            acc[0][ct] = __builtin_amdgcn_mfma_f32_16x16x32_bf16(ah0, bh, acc[0][ct], 0, 0, 0);
            acc[0][ct] = __builtin_amdgcn_mfma_f32_16x16x32_bf16(ah0, bl, acc[0][ct], 0, 0, 0);
            acc[0][ct] = __builtin_amdgcn_mfma_f32_16x16x32_bf16(al0, bh, acc[0][ct], 0, 0, 0);
            acc[1][ct] = __builtin_amdgcn_mfma_f32_16x16x32_bf16(ah1, bh, acc[1][ct], 0, 0, 0);
            acc[1][ct] = __builtin_amdgcn_mfma_f32_16x16x32_bf16(ah1, bl, acc[1][ct], 0, 0, 0);
            acc[1][ct] = __builtin_amdgcn_mfma_f32_16x16x32_bf16(al1, bh, acc[1][ct], 0, 0, 0);
        }
        __syncthreads();
    }

    // ---- fused stage 2 (in-wave): kdata[b,m] = sum_x tmp[m,x] * Eu[m,x]
    // C layout: col(x within tile) = ln15, row(m within tile) = 4*q + r
    #pragma unroll
    for (int r = 0; r < 4; ++r) {
        const int m = m0 + w * 16 + q * 4 + r;
        const float ku = ktraj[MM + m];
        float s0, c0, s16, c16;
        sincosf(ku * (float)(ln15 - 128), &s0, &c0);
        sincosf(ku * 16.0f, &s16, &c16);
        float er = c0, ei = -s0;       // Eu at x = ln15 - 128, step +16 per ct
        float sr = 0.f, si = 0.f;
        #pragma unroll
        for (int ct = 0; ct < 16; ++ct) {
            const float tr = acc[0][ct][r];
            const float ti = acc[1][ct][r];
            sr = fmaf(tr, er, fmaf(-ti, ei, sr));
            si = fmaf(tr, ei, fmaf(ti, er, si));
            const float nr = er * c16 + ei * s16;   // *= e^{-i*ku*16}
            const float ni = ei * c16 - er * s16;
            er = nr; ei = ni;
        }
        // reduce over the 16 lanes of this quad (masks <16 stay in-quad)
        #pragma unroll
        for (int off = 8; off >= 1; off >>= 1) {
            sr += __shfl_xor(sr, off);
            si += __shfl_xor(si, off);
        }
        if (ln15 == 0) {
            const float pr = pulsefac[m];
            const float pi = pulsefac[MM + m];
            const float vr = sr * pr - si * pi;
            const float vi = sr * pi + si * pr;
            out[b * 2 * MM + m]      = vr;
            out[b * 2 * MM + MM + m] = vi;
            out[VISAMP_OFF + b * MM + m] = sqrtf(vr * vr + vi * vi + EPSF);
        }
    }
}

// polynomial atan2 (A&S 4.4.49, err <= ~1e-5 rad), fully predicated
__device__ __forceinline__ float fast_atan2f(float y, float x)
{
    const float ax = fabsf(x), ay = fabsf(y);
    const float mx = fmaxf(ax, ay), mn = fminf(ax, ay);
    const float a  = mn / fmaxf(mx, 1e-37f);
    const float s  = a * a;
    float r = 0.0208351f;
    r = fmaf(r, s, -0.0851330f);
    r = fmaf(r, s,  0.1801410f);
    r = fmaf(r, s, -0.3302995f);
    r = fmaf(r, s,  0.9998660f);
    r *= a;
    r = (ay > ax) ? (1.57079632679f - r) : r;
    r = (x < 0.0f) ? (3.14159265359f - r) : r;
    return (y < 0.0f) ? -r : r;
}

// fused cphase + logcamp. Each block serves ONE batch (NCP % 256 == 0):
// stage that batch's vis (64 KB) into LDS with coalesced float4 loads, then
// all scattered reads hit LDS.
__global__ __launch_bounds__(256)
void gather_fused(const float* __restrict__ vis,
                  const float* __restrict__ sign,
                  const int* __restrict__ cind,
                  const int* __restrict__ caind,
                  float* __restrict__ out)
{
    __shared__ float sv[2 * MM];      // 64 KB: [0,MM)=re, [MM,2MM)=im

    const int i = blockIdx.x * 256 + threadIdx.x;
    const int b = i / NCP;
    const int n = i - b * NCP;

    {
        const float4* g4 = (const float4*)(vis + b * 2 * MM);
        float4* s4 = (float4*)sv;
        #pragma unroll
        for (int j = 0; j < (2 * MM / 4) / 256; ++j)
            s4[j * 256 + threadIdx.x] = g4[j * 256 + threadIdx.x];
    }
    __syncthreads();

    float cp = 0.f;
    #pragma unroll
    for (int k = 0; k < 3; ++k) {
        const int m = cind[k * NCP + n];
        cp += sign[k * NCP + n] * fast_atan2f(sv[MM + m], sv[m]);
    }
    out[CPH_OFF + i] = cp * 57.29577951308232f;   // 180/pi

    // logcamp = 0.5*log((p1*p2)/(p3*p4)), p = vr^2+vi^2+eps — one log call
    float p[4];
    #pragma unroll
    for (int k = 0; k < 4; ++k) {
        const int m = caind[k * NCA + n];
        const float vr = sv[m];
        const float vi = sv[MM + m];
        p[k] = vr * vr + vi * vi + EPSF;
    }
    out[LCA_OFF + i] = 0.5f * __logf((p[0] * p[1]) / (p[2] * p[3]));
}

extern "C" void kernel_launch(void* const* d_in, const int* in_sizes, int n_in,
                              void* d_out, int out_size, void* d_ws, size_t ws_size,
                              hipStream_t stream)
{
    const float* images   = (const float*)d_in[0];
    const float* ktraj    = (const float*)d_in[1];
    const float* pulsefac = (const float*)d_in[2];
    const float* csign    = (const float*)d_in[3];
    const int*   cind     = (const int*)d_in[4];
    const int*   caind    = (const int*)d_in[5];
    float* out = (float*)d_out;

    dim3 grid(MM / TMB, BB);
    nufft_vis_mfma<<<grid, 256, 0, stream>>>(images, ktraj, pulsefac, out);
    gather_fused<<<BB * NCP / 256, 256, 0, stream>>>(out, csign, cind, caind, out);
}

// Round 16
// 121.957 us; speedup vs baseline: 1.0117x; 1.0117x over previous
//
#include <hip/hip_runtime.h>
#include <cmath>

#define BB   8
#define NPIX 256
#define MM   8192
#define NCP  24576
#define NCA  24576
#define EPSF 1e-16f

#define KC   32    // K-chunk (y's per chunk) = one MFMA K-step
#define TMB  64    // m's per block

// ---- d_out layout (floats)
#define VIS_OFF    0
#define VISAMP_OFF (BB * 2 * MM)            // 131072
#define CPH_OFF    (VISAMP_OFF + BB * MM)   // 196608
#define LCA_OFF    (CPH_OFF + BB * NCP)     // 393216

typedef __bf16 bf16x8 __attribute__((ext_vector_type(8)));
typedef float  f32x4  __attribute__((ext_vector_type(4)));

// Window layout: a tile of R rows x 32 k is stored as windows of 512 elements
// (16 rows each); element (row, k) lives at
//   (row>>4)*512 + (k>>3)*128 + (row&15)*8 + (k&7)
// All staging writes and fragment reads have 16 B lane stride within each
// 16-lane phase -> 2-way bank aliasing only (free, m136). 16B-aligned b128s.
// SESSION RULES (hard-won):
//  - do NOT pipeline data between kernels through d_ws (R5/R6 sporadic
//    corruption); d_out dataflow is proven.
//  - acc = 128 AGPR + ~100 VGPR: ONLY 2 waves/SIMD fits (reg steps 64/128/256).
//    >=4 waves/SIMD spills catastrophically (R8/R10). Keep launch_bounds(256,2).
//  - NUMERICS: keep the full 3-term split (R12: 2-term -> cphase 361 deg).
//    Angle outputs forbid kdata shortcuts. Rotor drift ~2e-6 is OK.
//  - tsplit (bit-twiddle hi/lo) regressed (R15: VGPR 100->124, 62.5->67 us);
//    keep the cvt-roundtrip split.
//  - gather: ~58 us residual is INVARIANT across libm/poly/LDS-staged gather
//    implementations (R9/R11/R13) -> fixed harness cost; vis kernel is the
//    only controllable lever.
#define WIDX(row, k8) (((row) >> 4) * 512 + (k8) * 128 + ((row) & 15) * 8)

// exact-enough range reduction: returns theta == k*n (mod 2pi) in [-pi,pi].
// double path costs ~6 DP ops; result error ~2e-7 -> keeps libm sincosf on
// its FAST small-arg path (large args |k*n|<=402 take the ~10x slow path).
__device__ __forceinline__ float red2pi(float k, float n)
{
    const double t = (double)k * (double)n * 0.15915494309189535;  // /(2pi)
    const double f = t - rint(t);
    return (float)(f * 6.283185307179586);
}

// Block: 64 m's x 256 x's x 1 batch. Ev via rotor recurrences (3 small-arg
// trig anchors). 3-term split MFMA (hh, hl, lh) per plane.
__global__ __launch_bounds__(256, 2)
void nufft_vis_mfma(const float* __restrict__ images,
                    const float* __restrict__ ktraj,
                    const float* __restrict__ pulsefac,
                    float* __restrict__ out)
{
    __shared__ __align__(16) __bf16 sArh[TMB * KC];   // 4 KB  Evr hi
    __shared__ __align__(16) __bf16 sArl[TMB * KC];   // 4 KB  Evr lo
    __shared__ __align__(16) __bf16 sAih[TMB * KC];   // 4 KB  Evi hi
    __shared__ __align__(16) __bf16 sAil[TMB * KC];   // 4 KB  Evi lo
    __shared__ __align__(16) __bf16 sBh[NPIX * KC];   // 16 KB img hi
    __shared__ __align__(16) __bf16 sBl[NPIX * KC];   // 16 KB img lo

    const int tid  = threadIdx.x;
    const int m0   = blockIdx.x * TMB;
    const int b    = blockIdx.y;
    const int lane = tid & 63;
    const int w    = tid >> 6;        // wave 0..3
    const int ln15 = lane & 15;
    const int q    = lane >> 4;       // k-octet 0..3

    // A staging roles: thread (w, lane) computes Ev row=lane, k-octet=w.
    // 16B lane stride within each 16-lane phase -> 2-way (free).
    const float kvm = ktraj[m0 + lane];
    float r1s, r1c, r32s, r32c, as_, ac_;
    sincosf(kvm, &r1s, &r1c);                          // rot1: |kvm| <= pi
    sincosf(red2pi(kvm, 32.0f), &r32s, &r32c);         // rot32
    sincosf(red2pi(kvm, (float)(w * 8 - 128)), &as_, &ac_);  // anchor @ y0=0
    float anr = ac_, ani = -as_;
    const float* imgb = images + b * NPIX * NPIX + tid;  // B staging: x = tid
    const int ao = WIDX(lane, w);

    f32x4 acc[2][16];                 // [0]=real plane, [1]=imag plane
    #pragma unroll
    for (int rt = 0; rt < 2; ++rt)
        #pragma unroll
        for (int ct = 0; ct < 16; ++ct)
            acc[rt][ct] = (f32x4){0.f, 0.f, 0.f, 0.f};

    for (int y0 = 0; y0 < NPIX; y0 += KC) {
        // ---- stage A: Ev[m0+lane, y0+8*w .. +8) via anchor + rot1 recurrence
        {
            float er = anr, ei = ani;   // Ev = exp(-i*kv*(y-128))
            bf16x8 vrh, vrl, vih, vil;
            #pragma unroll
            for (int j = 0; j < 8; ++j) {
                __bf16 h = (__bf16)er;
                vrh[j] = h; vrl[j] = (__bf16)(er - (float)h);
                h = (__bf16)ei;
                vih[j] = h; vil[j] = (__bf16)(ei - (float)h);
                const float nr = er * r1c + ei * r1s;   // *= e^{-i*kvm}
                const float ni = ei * r1c - er * r1s;
                er = nr; ei = ni;
            }
            *(bf16x8*)&sArh[ao] = vrh;
            *(bf16x8*)&sArl[ao] = vrl;
            *(bf16x8*)&sAih[ao] = vih;
            *(bf16x8*)&sAil[ao] = vil;
            // advance anchor to next chunk: *= e^{-i*kvm*32}
            const float nr = anr * r32c + ani * r32s;
            const float ni = ani * r32c - anr * r32s;
            anr = nr; ani = ni;
        }
        // ---- stage B: img[b, y0..y0+31, x=tid] -> hi/lo, window layout
        #pragma unroll
        for (int gg = 0; gg < 4; ++gg) {
            bf16x8 bh, bl;
            #pragma unroll
            for (int j = 0; j < 8; ++j) {
                const float v = imgb[(y0 + gg * 8 + j) * NPIX];
                const __bf16 h = (__bf16)v;
                bh[j] = h; bl[j] = (__bf16)(v - (float)h);
            }
            const int bo = WIDX(tid, gg);
            *(bf16x8*)&sBh[bo] = bh;
            *(bf16x8*)&sBl[bo] = bl;
        }
        __syncthreads();

        // ---- MFMA: wave w owns A-rows [16w, 16w+16)
        const int aro = WIDX(w * 16 + ln15, q);
        const bf16x8 ah0 = *(const bf16x8*)&sArh[aro];
        const bf16x8 al0 = *(const bf16x8*)&sArl[aro];
        const bf16x8 ah1 = *(const bf16x8*)&sAih[aro];
        const bf16x8 al1 = *(const bf16x8*)&sAil[aro];

        #pragma unroll
        for (int ct = 0; ct < 16; ++ct) {
            const int bro = WIDX(ct * 16 + ln15, q);
            const bf16x8 bh = *(const bf16x8*)&sBh[bro];
            const bf16x8 bl = *(const bf16x8*)&sBl[bro];
            acc[0][ct] = __builtin_amdgcn_mfma_f32_16x16x32_bf16(ah0, bh, acc[0][ct], 0, 0, 0);
            acc[0][ct] = __builtin_amdgcn_mfma_f32_16x16x32_bf16(ah0, bl, acc[0][ct], 0, 0, 0);
            acc[0][ct] = __builtin_amdgcn_mfma_f32_16x16x32_bf16(al0, bh, acc[0][ct], 0, 0, 0);
            acc[1][ct] = __builtin_amdgcn_mfma_f32_16x16x32_bf16(ah1, bh, acc[1][ct], 0, 0, 0);
            acc[1][ct] = __builtin_amdgcn_mfma_f32_16x16x32_bf16(ah1, bl, acc[1][ct], 0, 0, 0);
            acc[1][ct] = __builtin_amdgcn_mfma_f32_16x16x32_bf16(al1, bh, acc[1][ct], 0, 0, 0);
        }
        __syncthreads();
    }

    // ---- fused stage 2 (in-wave): kdata[b,m] = sum_x tmp[m,x] * Eu[m,x]
    // C layout: col(x within tile) = ln15, row(m within tile) = 4*q + r
    #pragma unroll
    for (int r = 0; r < 4; ++r) {
        const int m = m0 + w * 16 + q * 4 + r;
        const float ku = ktraj[MM + m];
        float s0, c0, s16, c16;
        sincosf(red2pi(ku, (float)(ln15 - 128)), &s0, &c0);
        sincosf(red2pi(ku, 16.0f), &s16, &c16);
        float er = c0, ei = -s0;       // Eu at x = ln15 - 128, step +16 per ct
        float sr = 0.f, si = 0.f;
        #pragma unroll
        for (int ct = 0; ct < 16; ++ct) {
            const float tr = acc[0][ct][r];
            const float ti = acc[1][ct][r];
            sr = fmaf(tr, er, fmaf(-ti, ei, sr));
            si = fmaf(tr, ei, fmaf(ti, er, si));
            const float nr = er * c16 + ei * s16;   // *= e^{-i*ku*16}
            const float ni = ei * c16 - er * s16;
            er = nr; ei = ni;
        }
        // reduce over the 16 lanes of this quad (masks <16 stay in-quad)
        #pragma unroll
        for (int off = 8; off >= 1; off >>= 1) {
            sr += __shfl_xor(sr, off);
            si += __shfl_xor(si, off);
        }
        if (ln15 == 0) {
            const float pr = pulsefac[m];
            const float pi = pulsefac[MM + m];
            const float vr = sr * pr - si * pi;
            const float vi = sr * pi + si * pr;
            out[b * 2 * MM + m]      = vr;
            out[b * 2 * MM + MM + m] = vi;
            out[VISAMP_OFF + b * MM + m] = sqrtf(vr * vr + vi * vi + EPSF);
        }
    }
}

// polynomial atan2 (A&S 4.4.49, err <= ~1e-5 rad), fully predicated
__device__ __forceinline__ float fast_atan2f(float y, float x)
{
    const float ax = fabsf(x), ay = fabsf(y);
    const float mx = fmaxf(ax, ay), mn = fminf(ax, ay);
    const float a  = mn / fmaxf(mx, 1e-37f);
    const float s  = a * a;
    float r = 0.0208351f;
    r = fmaf(r, s, -0.0851330f);
    r = fmaf(r, s,  0.1801410f);
    r = fmaf(r, s, -0.3302995f);
    r = fmaf(r, s,  0.9998660f);
    r *= a;
    r = (ay > ax) ? (1.57079632679f - r) : r;
    r = (x < 0.0f) ? (3.14159265359f - r) : r;
    return (y < 0.0f) ? -r : r;
}

// fused cphase + logcamp. Each block serves ONE batch (NCP % 256 == 0):
// stage that batch's vis (64 KB) into LDS with coalesced float4 loads, then
// all scattered reads hit LDS.
__global__ __launch_bounds__(256)
void gather_fused(const float* __restrict__ vis,
                  const float* __restrict__ sign,
                  const int* __restrict__ cind,
                  const int* __restrict__ caind,
                  float* __restrict__ out)
{
    __shared__ float sv[2 * MM];      // 64 KB: [0,MM)=re, [MM,2MM)=im

    const int i = blockIdx.x * 256 + threadIdx.x;
    const int b = i / NCP;
    const int n = i - b * NCP;

    {
        const float4* g4 = (const float4*)(vis + b * 2 * MM);
        float4* s4 = (float4*)sv;
        #pragma unroll
        for (int j = 0; j < (2 * MM / 4) / 256; ++j)
            s4[j * 256 + threadIdx.x] = g4[j * 256 + threadIdx.x];
    }
    __syncthreads();

    float cp = 0.f;
    #pragma unroll
    for (int k = 0; k < 3; ++k) {
        const int m = cind[k * NCP + n];
        cp += sign[k * NCP + n] * fast_atan2f(sv[MM + m], sv[m]);
    }
    out[CPH_OFF + i] = cp * 57.29577951308232f;   // 180/pi

    // logcamp = 0.5*log((p1*p2)/(p3*p4)), p = vr^2+vi^2+eps — one log call
    float p[4];
    #pragma unroll
    for (int k = 0; k < 4; ++k) {
        const int m = caind[k * NCA + n];
        const float vr = sv[m];
        const float vi = sv[MM + m];
        p[k] = vr * vr + vi * vi + EPSF;
    }
    out[LCA_OFF + i] = 0.5f * __logf((p[0] * p[1]) / (p[2] * p[3]));
}

extern "C" void kernel_launch(void* const* d_in, const int* in_sizes, int n_in,
                              void* d_out, int out_size, void* d_ws, size_t ws_size,
                              hipStream_t stream)
{
    const float* images   = (const float*)d_in[0];
    const float* ktraj    = (const float*)d_in[1];
    const float* pulsefac = (const float*)d_in[2];
    const float* csign    = (const float*)d_in[3];
    const int*   cind     = (const int*)d_in[4];
    const int*   caind    = (const int*)d_in[5];
    float* out = (float*)d_out;

    dim3 grid(MM / TMB, BB);
    nufft_vis_mfma<<<grid, 256, 0, stream>>>(images, ktraj, pulsefac, out);
    gather_fused<<<BB * NCP / 256, 256, 0, stream>>>(out, csign, cind, caind, out);
}

// Round 17
// 115.501 us; speedup vs baseline: 1.0682x; 1.0559x over previous
//
#include <hip/hip_runtime.h>
#include <cmath>

#define BB   8
#define NPIX 256
#define MM   8192
#define NCP  24576
#define NCA  24576
#define EPSF 1e-16f

#define KC   32    // K-chunk (y's per chunk) = one MFMA K-step
#define TMB  128   // m's per block
#define NT   512   // threads per block (8 waves)

// ---- d_out layout (floats)
#define VIS_OFF    0
#define VISAMP_OFF (BB * 2 * MM)            // 131072
#define CPH_OFF    (VISAMP_OFF + BB * MM)   // 196608
#define LCA_OFF    (CPH_OFF + BB * NCP)     // 393216

typedef __bf16 bf16x8 __attribute__((ext_vector_type(8)));
typedef float  f32x4  __attribute__((ext_vector_type(4)));

// Window layout: a tile of R rows x 32 k is stored as windows of 512 elements
// (16 rows each); element (row, k) lives at
//   (row>>4)*512 + (k>>3)*128 + (row&15)*8 + (k&7)
// All staging writes and fragment reads have 16 B lane stride within each
// 16-lane phase -> 2-way bank aliasing only (free, m136). 16B-aligned b128s.
// SESSION RULES (hard-won):
//  - do NOT pipeline data between kernels through d_ws (R5/R6 sporadic
//    corruption); d_out dataflow is proven.
//  - acc = 128 AGPR + ~124 VGPR = 252: needs 256-reg budget. launch_bounds
//    2nd arg MUST be 2 (256-reg cap). R10's (512,4) capped at 128 -> 385 MB
//    scratch spill, 3x slower. WRITE_SIZE is the spill tripwire (768 KB ok).
//  - NUMERICS: keep the full 3-term split (R12: 2-term -> cphase 361 deg).
//    Angle outputs forbid kdata shortcuts. Rotor drift ~2e-6 is OK.
//  - tsplit (bit-twiddle hi/lo) regressed (R15: VGPR 100->124, 62.5->67 us);
//    keep the cvt-roundtrip split.
//  - trig slow-path theory dead (R16 range reduction: neutral). VALUBusy is
//    the conversion bulk itself -> reduce TOTAL staging work (this round:
//    TMB=128/512T halves per-image conversion redundancy).
//  - gather: ~58 us residual is INVARIANT across libm/poly/LDS-staged gather
//    implementations (R9/R11/R13) -> fixed harness cost; vis kernel is the
//    only controllable lever.
#define WIDX(row, k8) (((row) >> 4) * 512 + (k8) * 128 + ((row) & 15) * 8)

// range reduction: theta == k*n (mod 2pi) in [-pi,pi] (keeps sincosf fast).
__device__ __forceinline__ float red2pi(float k, float n)
{
    const double t = (double)k * (double)n * 0.15915494309189535;  // /(2pi)
    const double f = t - rint(t);
    return (float)(f * 6.283185307179586);
}

// Block: 128 m's x 256 x's x 1 batch, 8 waves. Ev via rotor recurrences.
// 3-term split MFMA (hh, hl, lh) per plane.
__global__ __launch_bounds__(NT, 2)
void nufft_vis_mfma(const float* __restrict__ images,
                    const float* __restrict__ ktraj,
                    const float* __restrict__ pulsefac,
                    float* __restrict__ out)
{
    __shared__ __align__(16) __bf16 sArh[TMB * KC];   // 8 KB  Evr hi
    __shared__ __align__(16) __bf16 sArl[TMB * KC];   // 8 KB  Evr lo
    __shared__ __align__(16) __bf16 sAih[TMB * KC];   // 8 KB  Evi hi
    __shared__ __align__(16) __bf16 sAil[TMB * KC];   // 8 KB  Evi lo
    __shared__ __align__(16) __bf16 sBh[NPIX * KC];   // 16 KB img hi
    __shared__ __align__(16) __bf16 sBl[NPIX * KC];   // 16 KB img lo

    const int tid  = threadIdx.x;
    const int m0   = blockIdx.x * TMB;
    const int b    = blockIdx.y;
    const int lane = tid & 63;
    const int w    = tid >> 6;        // wave 0..7
    const int ln15 = lane & 15;
    const int q    = lane >> 4;       // k-octet 0..3

    // A staging: thread stages Ev row = tid&127, k-octet = tid>>7.
    // Write bytes: (row>>4)*1024 + oct*256 + (row&15)*16 -> 16B lane stride
    // within each 16-lane phase -> 2-way (free).
    const int arow = tid & 127;
    const int aoct = tid >> 7;        // 0..3
    const float kvm = ktraj[m0 + arow];
    float r1s, r1c, r32s, r32c, as_, ac_;
    sincosf(kvm, &r1s, &r1c);                          // rot1: |kvm| <= pi
    sincosf(red2pi(kvm, 32.0f), &r32s, &r32c);         // rot32
    sincosf(red2pi(kvm, (float)(aoct * 8 - 128)), &as_, &ac_);  // anchor @ y0=0
    float anr = ac_, ani = -as_;
    const int ao = WIDX(arow, aoct);

    // B staging: x = tid&255, y-octet pair = (tid>>8)*2 .. +1
    const int bx    = tid & 255;
    const int bhalf = tid >> 8;       // 0..1
    const float* imgb = images + b * NPIX * NPIX + bx;

    f32x4 acc[2][16];                 // [0]=real plane, [1]=imag plane
    #pragma unroll
    for (int rt = 0; rt < 2; ++rt)
        #pragma unroll
        for (int ct = 0; ct < 16; ++ct)
            acc[rt][ct] = (f32x4){0.f, 0.f, 0.f, 0.f};

    for (int y0 = 0; y0 < NPIX; y0 += KC) {
        // ---- stage A: Ev[m0+arow, y0+8*aoct .. +8) via anchor + rot1
        {
            float er = anr, ei = ani;   // Ev = exp(-i*kv*(y-128))
            bf16x8 vrh, vrl, vih, vil;
            #pragma unroll
            for (int j = 0; j < 8; ++j) {
                __bf16 h = (__bf16)er;
                vrh[j] = h; vrl[j] = (__bf16)(er - (float)h);
                h = (__bf16)ei;
                vih[j] = h; vil[j] = (__bf16)(ei - (float)h);
                const float nr = er * r1c + ei * r1s;   // *= e^{-i*kvm}
                const float ni = ei * r1c - er * r1s;
                er = nr; ei = ni;
            }
            *(bf16x8*)&sArh[ao] = vrh;
            *(bf16x8*)&sArl[ao] = vrl;
            *(bf16x8*)&sAih[ao] = vih;
            *(bf16x8*)&sAil[ao] = vil;
            // advance anchor to next chunk: *= e^{-i*kvm*32}
            const float nr = anr * r32c + ani * r32s;
            const float ni = ani * r32c - anr * r32s;
            anr = nr; ani = ni;
        }
        // ---- stage B: img[b, y-octets, x=bx] -> hi/lo, window layout
        #pragma unroll
        for (int oo = 0; oo < 2; ++oo) {
            const int oct = bhalf * 2 + oo;
            bf16x8 bh, bl;
            #pragma unroll
            for (int j = 0; j < 8; ++j) {
                const float v = imgb[(y0 + oct * 8 + j) * NPIX];
                const __bf16 h = (__bf16)v;
                bh[j] = h; bl[j] = (__bf16)(v - (float)h);
            }
            const int bo = WIDX(bx, oct);
            *(bf16x8*)&sBh[bo] = bh;
            *(bf16x8*)&sBl[bo] = bl;
        }
        __syncthreads();

        // ---- MFMA: wave w owns A-rows [16w, 16w+16)
        const int aro = WIDX(w * 16 + ln15, q);
        const bf16x8 ah0 = *(const bf16x8*)&sArh[aro];
        const bf16x8 al0 = *(const bf16x8*)&sArl[aro];
        const bf16x8 ah1 = *(const bf16x8*)&sAih[aro];
        const bf16x8 al1 = *(const bf16x8*)&sAil[aro];

        #pragma unroll
        for (int ct = 0; ct < 16; ++ct) {
            const int bro = WIDX(ct * 16 + ln15, q);
            const bf16x8 bh = *(const bf16x8*)&sBh[bro];
            const bf16x8 bl = *(const bf16x8*)&sBl[bro];
            acc[0][ct] = __builtin_amdgcn_mfma_f32_16x16x32_bf16(ah0, bh, acc[0][ct], 0, 0, 0);
            acc[0][ct] = __builtin_amdgcn_mfma_f32_16x16x32_bf16(ah0, bl, acc[0][ct], 0, 0, 0);
            acc[0][ct] = __builtin_amdgcn_mfma_f32_16x16x32_bf16(al0, bh, acc[0][ct], 0, 0, 0);
            acc[1][ct] = __builtin_amdgcn_mfma_f32_16x16x32_bf16(ah1, bh, acc[1][ct], 0, 0, 0);
            acc[1][ct] = __builtin_amdgcn_mfma_f32_16x16x32_bf16(ah1, bl, acc[1][ct], 0, 0, 0);
            acc[1][ct] = __builtin_amdgcn_mfma_f32_16x16x32_bf16(al1, bh, acc[1][ct], 0, 0, 0);
        }
        __syncthreads();
    }

    // ---- fused stage 2 (in-wave): kdata[b,m] = sum_x tmp[m,x] * Eu[m,x]
    // C layout: col(x within tile) = ln15, row(m within tile) = 4*q + r
    #pragma unroll
    for (int r = 0; r < 4; ++r) {
        const int m = m0 + w * 16 + q * 4 + r;
        const float ku = ktraj[MM + m];
        float s0, c0, s16, c16;
        sincosf(red2pi(ku, (float)(ln15 - 128)), &s0, &c0);
        sincosf(red2pi(ku, 16.0f), &s16, &c16);
        float er = c0, ei = -s0;       // Eu at x = ln15 - 128, step +16 per ct
        float sr = 0.f, si = 0.f;
        #pragma unroll
        for (int ct = 0; ct < 16; ++ct) {
            const float tr = acc[0][ct][r];
            const float ti = acc[1][ct][r];
            sr = fmaf(tr, er, fmaf(-ti, ei, sr));
            si = fmaf(tr, ei, fmaf(ti, er, si));
            const float nr = er * c16 + ei * s16;   // *= e^{-i*ku*16}
            const float ni = ei * c16 - er * s16;
            er = nr; ei = ni;
        }
        // reduce over the 16 lanes of this quad (masks <16 stay in-quad)
        #pragma unroll
        for (int off = 8; off >= 1; off >>= 1) {
            sr += __shfl_xor(sr, off);
            si += __shfl_xor(si, off);
        }
        if (ln15 == 0) {
            const float pr = pulsefac[m];
            const float pi = pulsefac[MM + m];
            const float vr = sr * pr - si * pi;
            const float vi = sr * pi + si * pr;
            out[b * 2 * MM + m]      = vr;
            out[b * 2 * MM + MM + m] = vi;
            out[VISAMP_OFF + b * MM + m] = sqrtf(vr * vr + vi * vi + EPSF);
        }
    }
}

// polynomial atan2 (A&S 4.4.49, err <= ~1e-5 rad), fully predicated
__device__ __forceinline__ float fast_atan2f(float y, float x)
{
    const float ax = fabsf(x), ay = fabsf(y);
    const float mx = fmaxf(ax, ay), mn = fminf(ax, ay);
    const float a  = mn / fmaxf(mx, 1e-37f);
    const float s  = a * a;
    float r = 0.0208351f;
    r = fmaf(r, s, -0.0851330f);
    r = fmaf(r, s,  0.1801410f);
    r = fmaf(r, s, -0.3302995f);
    r = fmaf(r, s,  0.9998660f);
    r *= a;
    r = (ay > ax) ? (1.57079632679f - r) : r;
    r = (x < 0.0f) ? (3.14159265359f - r) : r;
    return (y < 0.0f) ? -r : r;
}

// fused cphase + logcamp. Each block serves ONE batch (NCP % 256 == 0):
// stage that batch's vis (64 KB) into LDS with coalesced float4 loads, then
// all scattered reads hit LDS.
__global__ __launch_bounds__(256)
void gather_fused(const float* __restrict__ vis,
                  const float* __restrict__ sign,
                  const int* __restrict__ cind,
                  const int* __restrict__ caind,
                  float* __restrict__ out)
{
    __shared__ float sv[2 * MM];      // 64 KB: [0,MM)=re, [MM,2MM)=im

    const int i = blockIdx.x * 256 + threadIdx.x;
    const int b = i / NCP;
    const int n = i - b * NCP;

    {
        const float4* g4 = (const float4*)(vis + b * 2 * MM);
        float4* s4 = (float4*)sv;
        #pragma unroll
        for (int j = 0; j < (2 * MM / 4) / 256; ++j)
            s4[j * 256 + threadIdx.x] = g4[j * 256 + threadIdx.x];
    }
    __syncthreads();

    float cp = 0.f;
    #pragma unroll
    for (int k = 0; k < 3; ++k) {
        const int m = cind[k * NCP + n];
        cp += sign[k * NCP + n] * fast_atan2f(sv[MM + m], sv[m]);
    }
    out[CPH_OFF + i] = cp * 57.29577951308232f;   // 180/pi

    // logcamp = 0.5*log((p1*p2)/(p3*p4)), p = vr^2+vi^2+eps — one log call
    float p[4];
    #pragma unroll
    for (int k = 0; k < 4; ++k) {
        const int m = caind[k * NCA + n];
        const float vr = sv[m];
        const float vi = sv[MM + m];
        p[k] = vr * vr + vi * vi + EPSF;
    }
    out[LCA_OFF + i] = 0.5f * __logf((p[0] * p[1]) / (p[2] * p[3]));
}

extern "C" void kernel_launch(void* const* d_in, const int* in_sizes, int n_in,
                              void* d_out, int out_size, void* d_ws, size_t ws_size,
                              hipStream_t stream)
{
    const float* images   = (const float*)d_in[0];
    const float* ktraj    = (const float*)d_in[1];
    const float* pulsefac = (const float*)d_in[2];
    const float* csign    = (const float*)d_in[3];
    const int*   cind     = (const int*)d_in[4];
    const int*   caind    = (const int*)d_in[5];
    float* out = (float*)d_out;

    dim3 grid(MM / TMB, BB);
    nufft_vis_mfma<<<grid, NT, 0, stream>>>(images, ktraj, pulsefac, out);
    gather_fused<<<BB * NCP / 256, 256, 0, stream>>>(out, csign, cind, caind, out);
}